// Round 4
// baseline (1119.177 us; speedup 1.0000x reference)
//
#include <hip/hip_runtime.h>
#include <stdint.h>

typedef unsigned short u16;
typedef unsigned int   u32;
using f32x16 = __attribute__((ext_vector_type(16))) float;
using bf16x8 = __attribute__((ext_vector_type(8))) short;   // 8 bf16 codes (4 VGPRs)

// ---------------- fp32 -> bf16 (RNE) conversion, vectorized ----------------
__device__ __forceinline__ u16 f2bf(float f) {
  union { float f; u32 u; } c; c.f = f;
  return (u16)((c.u + 0x7FFFu + ((c.u >> 16) & 1u)) >> 16);
}

__global__ void cvt_f32_bf16(const float* __restrict__ in, u16* __restrict__ out, int n8) {
  int i = blockIdx.x * blockDim.x + threadIdx.x;
  const int stride = gridDim.x * blockDim.x;
  for (; i < n8; i += stride) {
    float4 v0 = reinterpret_cast<const float4*>(in)[2 * i];
    float4 v1 = reinterpret_cast<const float4*>(in)[2 * i + 1];
    uint4 o;
    o.x = (u32)f2bf(v0.x) | ((u32)f2bf(v0.y) << 16);
    o.y = (u32)f2bf(v0.z) | ((u32)f2bf(v0.w) << 16);
    o.z = (u32)f2bf(v1.x) | ((u32)f2bf(v1.y) << 16);
    o.w = (u32)f2bf(v1.z) | ((u32)f2bf(v1.w) << 16);
    reinterpret_cast<uint4*>(out)[i] = o;
  }
}

// async global->LDS, 16B per lane, dest = wave-uniform base + lane*16
#define GLD_LDS16(SRC, DST)                                      \
  __builtin_amdgcn_global_load_lds(                              \
      (const __attribute__((address_space(1))) void*)(SRC),      \
      (__attribute__((address_space(3))) void*)(DST), 16, 0, 0)

#define SCHED0() __builtin_amdgcn_sched_barrier(0)
#define BAR()    __builtin_amdgcn_s_barrier()
#define PRIO(x)  __builtin_amdgcn_s_setprio(x)

// ---------------- 256x256 8-phase bf16 GEMM: C = scale*(A @ B^T) + bias ----------------
// BM=BN=256, BK=64, 8 waves (2M x 4N), per-wave 128x64 output = 4x2 32x32 frags,
// v_mfma_f32_32x32x16_bf16 (4061 FLOP/cyc ceiling vs 3379 for 16x16x32).
// LDS: 2 buf x (A 32KB + B 32KB) = 128 KiB. XOR slot swizzle: phys_slot = kslot ^ (row&7),
// staged via inverse-swizzled global source (global_load_lds writes linearly).
// Schedule per K-tile (4 phases, balanced reads {8,4,8,4}):
//   p0: LDA mf01 (8) | stage A-h0(t+1)->buf^1 | BAR | MFMA (mf01 x nf0)
//   p1: LDB nf1  (4) | stage A-h1(t+1)->buf^1 | BAR | MFMA (mf01 x nf1) | BAR
//   p2: LDA mf23 (8) | stage B-h0(t+2)->cur   | BAR | MFMA (mf23 x nf0)
//   p3: vmcnt(6)+BAR (B(t+1) landed) | LDB-next nf0 from buf^1 (4) |
//       stage B-h1(t+2)->cur | MFMA (mf23 x nf1, dep-free) | vmcnt(4)+BAR
__global__ __launch_bounds__(512, 2)
void gemm256_8ph(const u16* __restrict__ A,   // [M][K] bf16
                 const u16* __restrict__ B,   // [N][K] bf16
                 const float* __restrict__ scale_p,
                 const float* __restrict__ bias,
                 float* __restrict__ C,       // [M][N] fp32
                 int Nn, int Kk, int NT) {
  __shared__ u16 lds[2][2][256 * 64];  // [buf][A/B][256 rows x 64 cols]

  const int tid  = threadIdx.x;
  const int lane = tid & 63;
  const int wave = tid >> 6;       // 0..7
  const int wr = wave >> 2;        // 0..1 (M)
  const int wc = wave & 3;         // 0..3 (N)

  // T1: XCD-aware swizzle (gridDim.x == 2048, divisible by 8)
  const int bid = blockIdx.x;
  const int cpx = gridDim.x >> 3;
  const int wg  = (bid & 7) * cpx + (bid >> 3);
  const int mt = wg / NT, nt = wg % NT;
  const int m0 = mt * 256, n0 = nt * 256;

  const int rg  = lane >> 3;             // row in 8-row staging group
  const int ss  = (lane & 7) ^ rg;       // inverse-swizzled source k-slot
  const int r32 = lane & 31;             // fragment row/col within 32
  const int l5  = lane >> 5;             // k-half (0..1)

  // per-thread global staging bases (row = h*128 + wave*16 + j*8 + rg, col = kt*64 + ss*8)
  const u16* ga = A + ((size_t)m0 + wave * 16 + rg) * Kk + ss * 8;
  const u16* gb = B + ((size_t)n0 + wave * 16 + rg) * Kk + ss * 8;

  // LDS element offsets for 32x32x16 fragment reads:
  // frag k-slot = 2*ks + l5, phys = (2*ks + l5) ^ (row&7) = (l5 ^ (row&7)) ^ 2*ks
  // => element addr = base ^ (ks<<4); mf/nf frag step = 32 rows * 64 = 2048 elems
  const int aoff = (wr * 128 + r32) * 64 + (l5 ^ (r32 & 7)) * 8;
  const int boff = (wc * 64  + r32) * 64 + (l5 ^ (r32 & 7)) * 8;

  f32x16 acc[4][2];   // [mf][nf], 128 accum regs
#pragma unroll
  for (int i = 0; i < 4; ++i)
#pragma unroll
    for (int j = 0; j < 2; ++j)
      acc[i][j] = (f32x16){0.f};

  bf16x8 af[2][4];   // current mf-group (mh*2 + i), ks 0..3
  bf16x8 bfe[4];     // B frag nf0, ks 0..3 (read one phase early, at prev p3)
  bf16x8 bfo[4];     // B frag nf1, ks 0..3 (same-phase read at p1)

  // stage one half-tile: operand op (0=A,1=B), half h, into buffer bfi_, source k-tile kt
#define STAGE(bfi_, op_, h_, kt_) do {                                          \
    const u16* _g = ((op_) ? gb : ga) + (size_t)(kt_) * 64 + (size_t)(h_) * 128 * Kk; \
    u16* _d = &lds[bfi_][op_][(h_) * 128 * 64 + wave * 16 * 64];                \
    GLD_LDS16(_g,          _d);                                                 \
    GLD_LDS16(_g + 8 * Kk, _d + 512);                                           \
  } while (0)

#define LDA4(la_, mh_) do {                                                     \
    _Pragma("unroll") for (int _i = 0; _i < 2; ++_i)                            \
    _Pragma("unroll") for (int _k = 0; _k < 4; ++_k)                            \
      af[_i][_k] = *reinterpret_cast<const bf16x8*>(                            \
          (la_) + ((aoff + ((mh_) * 2 + _i) * 2048) ^ (_k << 4)));              \
    } while (0)

#define LDBE(lb_) do {                                                          \
    _Pragma("unroll") for (int _k = 0; _k < 4; ++_k)                            \
      bfe[_k] = *reinterpret_cast<const bf16x8*>((lb_) + (boff ^ (_k << 4)));   \
    } while (0)

#define LDBO(lb_) do {                                                          \
    _Pragma("unroll") for (int _k = 0; _k < 4; ++_k)                            \
      bfo[_k] = *reinterpret_cast<const bf16x8*>(                               \
          (lb_) + ((boff + 2048) ^ (_k << 4)));                                 \
    } while (0)

#define MFMA_Q(mh_, BF_, nf_)                                                   \
  _Pragma("unroll") for (int ks = 0; ks < 4; ++ks)                              \
  _Pragma("unroll") for (int i = 0; i < 2; ++i)                                 \
    acc[(mh_) * 2 + i][nf_] = __builtin_amdgcn_mfma_f32_32x32x16_bf16(          \
        af[i][ks], BF_[ks], acc[(mh_) * 2 + i][nf_], 0, 0, 0)

  const int KT = Kk >> 6;

  // ---- prologue: tile0 (A0,A1,B0,B1)->buf0 + tile1 (B0,B1)->buf1; drain tile0 ----
  STAGE(0, 0, 0, 0); STAGE(0, 0, 1, 0); STAGE(0, 1, 0, 0); STAGE(0, 1, 1, 0);
  STAGE(1, 1, 0, 1); STAGE(1, 1, 1, 1);
  asm volatile("s_waitcnt vmcnt(4)" ::: "memory");
  SCHED0(); BAR();
  LDBE((const u16*)&lds[0][1][0]);   // pre-read bfe = B nf0 (tile0)

#define TILE(t_, CUR_) do {                                                     \
    const u16* la  = &lds[CUR_][0][0];                                          \
    const u16* lb  = &lds[CUR_][1][0];                                          \
    const u16* lbn = &lds[CUR_ ^ 1][1][0];                                      \
    const int kt1 = ((t_) + 1 < KT) ? (t_) + 1 : KT - 1;                        \
    const int kt2 = ((t_) + 2 < KT) ? (t_) + 2 : KT - 1;                        \
    /* p0 */                                                                    \
    LDA4(la, 0);                                                                \
    STAGE(CUR_ ^ 1, 0, 0, kt1);                                                 \
    SCHED0(); BAR();                                                            \
    PRIO(1); MFMA_Q(0, bfe, 0); PRIO(0);                                        \
    /* p1 */                                                                    \
    LDBO(lb);                                                                   \
    STAGE(CUR_ ^ 1, 0, 1, kt1);                                                 \
    SCHED0(); BAR();                                                            \
    PRIO(1); MFMA_Q(0, bfo, 1); PRIO(0);                                        \
    SCHED0(); BAR();                                                            \
    /* p2 */                                                                    \
    LDA4(la, 1);                                                                \
    STAGE(CUR_, 1, 0, kt2);                                                     \
    SCHED0(); BAR();                                                            \
    PRIO(1); MFMA_Q(1, bfe, 0); PRIO(0);                                        \
    /* p3 */                                                                    \
    asm volatile("s_waitcnt vmcnt(6)" ::: "memory");                            \
    SCHED0(); BAR();                                                            \
    LDBE(lbn);                                                                  \
    STAGE(CUR_, 1, 1, kt2);                                                     \
    PRIO(1); MFMA_Q(1, bfo, 1); PRIO(0);                                        \
    asm volatile("s_waitcnt vmcnt(4)" ::: "memory");                            \
    SCHED0(); BAR();                                                            \
  } while (0)

  for (int kt = 0; kt < KT; kt += 2) {
    TILE(kt, 0);
    TILE(kt + 1, 1);
  }

  // ---- epilogue: out = acc*scale + bias ----
  const float sc = scale_p[0];
  float bv[2];
#pragma unroll
  for (int nf = 0; nf < 2; ++nf) bv[nf] = bias[n0 + wc * 64 + nf * 32 + r32];
#pragma unroll
  for (int mf = 0; mf < 4; ++mf) {
#pragma unroll
    for (int r = 0; r < 16; ++r) {
      // C/D layout (32x32x16): col = lane&31, row = (r&3) + 8*(r>>2) + 4*(lane>>5)
      const int row = m0 + wr * 128 + mf * 32 + (r & 3) + 8 * (r >> 2) + 4 * l5;
      float* cp = C + (size_t)row * Nn + (n0 + wc * 64 + r32);
#pragma unroll
      for (int nf = 0; nf < 2; ++nf)
        cp[nf * 32] = acc[mf][nf][r] * sc + bv[nf];
    }
  }
#undef STAGE
#undef LDA4
#undef LDBE
#undef LDBO
#undef MFMA_Q
#undef TILE
}

extern "C" void kernel_launch(void* const* d_in, const int* in_sizes, int n_in,
                              void* d_out, int out_size, void* d_ws, size_t ws_size,
                              hipStream_t stream) {
  (void)n_in; (void)out_size; (void)ws_size;
  const float* x  = (const float*)d_in[0];   // [M][K] fp32
  const float* w  = (const float*)d_in[1];   // [N][K] fp32 (fp8-representable values)
  const float* sc = (const float*)d_in[2];   // [1]
  const float* bs = (const float*)d_in[3];   // [N]
  float* out = (float*)d_out;                // [M][N] fp32

  const int N = in_sizes[3];        // 16384
  const int K = in_sizes[1] / N;    // 4096
  const int M = in_sizes[0] / K;    // 8192

  u16* xb = (u16*)d_ws;                      // [M][K] bf16  (64 MB)
  u16* wb = xb + (size_t)M * K;              // [N][K] bf16  (128 MB)

  cvt_f32_bf16<<<2048, 256, 0, stream>>>(x, xb, (M * K) / 8);
  cvt_f32_bf16<<<2048, 256, 0, stream>>>(w, wb, (N * K) / 8);

  const int NT = N / 256;
  const int nwg = (M / 256) * NT;            // 2048, % 8 == 0
  gemm256_8ph<<<nwg, 512, 0, stream>>>(xb, wb, sc, bs, out, N, K, NT);
}

// Round 5
// 1018.119 us; speedup vs baseline: 1.0993x; 1.0993x over previous
//
#include <hip/hip_runtime.h>
#include <stdint.h>

typedef unsigned short u16;
typedef unsigned int   u32;
using f32x4  = __attribute__((ext_vector_type(4))) float;
using bf16x8 = __attribute__((ext_vector_type(8))) short;   // 8 bf16 codes (4 VGPRs)

// ---------------- fp32 -> bf16 (RNE) conversion, vectorized ----------------
__device__ __forceinline__ u16 f2bf(float f) {
  union { float f; u32 u; } c; c.f = f;
  return (u16)((c.u + 0x7FFFu + ((c.u >> 16) & 1u)) >> 16);
}

__global__ void cvt_f32_bf16(const float* __restrict__ in, u16* __restrict__ out, int n8) {
  int i = blockIdx.x * blockDim.x + threadIdx.x;
  const int stride = gridDim.x * blockDim.x;
  for (; i < n8; i += stride) {
    float4 v0 = reinterpret_cast<const float4*>(in)[2 * i];
    float4 v1 = reinterpret_cast<const float4*>(in)[2 * i + 1];
    uint4 o;
    o.x = (u32)f2bf(v0.x) | ((u32)f2bf(v0.y) << 16);
    o.y = (u32)f2bf(v0.z) | ((u32)f2bf(v0.w) << 16);
    o.z = (u32)f2bf(v1.x) | ((u32)f2bf(v1.y) << 16);
    o.w = (u32)f2bf(v1.z) | ((u32)f2bf(v1.w) << 16);
    reinterpret_cast<uint4*>(out)[i] = o;
  }
}

// async global->LDS, 16B per lane, dest = wave-uniform base + lane*16
#define GLD_LDS16(SRC, DST)                                      \
  __builtin_amdgcn_global_load_lds(                              \
      (const __attribute__((address_space(1))) void*)(SRC),      \
      (__attribute__((address_space(3))) void*)(DST), 16, 0, 0)

#define SCHED0() __builtin_amdgcn_sched_barrier(0)
#define BAR()    __builtin_amdgcn_s_barrier()
#define PRIO(x)  __builtin_amdgcn_s_setprio(x)

// ---------------- 256x256 8-phase bf16 GEMM: C = scale*(A @ B^T) + bias ----------------
// BM=BN=256, BK=64, 8 waves (2M x 4N), per-wave 128x64 output (8x4 16x16x32 frags).
// LDS: 2 buf x (A 32KB + B 32KB) = 128 KiB. XOR slot swizzle: phys_slot = kslot ^ (row&7),
// staged via inverse-swizzled global source (global_load_lds writes linearly).
// Fully register-pipelined schedule: every MFMA consumes frags ds_read in an EARLIER
// phase; reads for phase p+1 issue after phase p's MFMA cluster. Staging is 2 tiles
// ahead into the CURRENT buffer (regions dead by barrier-ordered last-read analysis):
//   p0: BAR | MFMA mh0*bfe           | read bfo(t)        [4]
//   p1: BAR | MFMA mh0*bfo           | read af=mh1(t)     [8]
//   p2: BAR | stage B(t+2)->cur      | MFMA mh1*bfe       [0]
//   p3: vmcnt(4) BAR | stage A(t+2)->cur | MFMA mh1*bfo   | read af=mh0(t+1)[8], bfe(t+1)[4]
// Single vmcnt(4)/tile: drained loads are >=4 phases old (issued t-1 p3) -> no stall.
__global__ __launch_bounds__(512, 2)
void gemm256_8ph(const u16* __restrict__ A,   // [M][K] bf16
                 const u16* __restrict__ B,   // [N][K] bf16
                 const float* __restrict__ scale_p,
                 const float* __restrict__ bias,
                 float* __restrict__ C,       // [M][N] fp32
                 int Nn, int Kk, int NT) {
  __shared__ u16 lds[2][2][256 * 64];  // [buf][A/B][256 rows x 64 cols]

  const int tid  = threadIdx.x;
  const int lane = tid & 63;
  const int wave = tid >> 6;       // 0..7
  const int wr = wave >> 2;        // 0..1 (M)
  const int wc = wave & 3;         // 0..3 (N)

  // T1: XCD-aware swizzle (gridDim.x == 2048, divisible by 8)
  const int bid = blockIdx.x;
  const int cpx = gridDim.x >> 3;
  const int wg  = (bid & 7) * cpx + (bid >> 3);
  const int mt = wg / NT, nt = wg % NT;
  const int m0 = mt * 256, n0 = nt * 256;

  const int rg  = lane >> 3;             // row in 8-row staging group
  const int ss  = (lane & 7) ^ rg;       // inverse-swizzled source k-slot
  const int r16 = lane & 15;
  const int kq  = lane >> 4;

  // per-thread global staging bases (row = h*128 + wave*16 + j*8 + rg, col = kt*64 + ss*8)
  const u16* ga = A + ((size_t)m0 + wave * 16 + rg) * Kk + ss * 8;
  const u16* gb = B + ((size_t)n0 + wave * 16 + rg) * Kk + ss * 8;

  // LDS element offsets for fragment reads (slot = (ks*4+kq) ^ (row&7); ks flips bit 5)
  const int aoff = (wr * 128 + r16) * 64 + (kq ^ (r16 & 7)) * 8;  // + mi*1024, ^ (ks*32)
  const int boff = (wc * 64  + r16) * 64 + (kq ^ (r16 & 7)) * 8;  // + ni*1024, ^ (ks*32)

  f32x4 acc[8][4];
#pragma unroll
  for (int i = 0; i < 8; ++i)
#pragma unroll
    for (int j = 0; j < 4; ++j)
      acc[i][j] = (f32x4){0.f, 0.f, 0.f, 0.f};

  bf16x8 af[4][2];   // current mi-group (mh*4 + i), ks 0/1 (reused for mh0/mh1)
  bf16x8 bfe[2][2];  // B frags ni0,1 (read one tile early, at prev p3)
  bf16x8 bfo[2][2];  // B frags ni2,3 (read at p0, used p1 and p3)

  // stage one half-tile: operand op (0=A,1=B), half h, into buffer bfi_, source k-tile kt
#define STAGE(bfi_, op_, h_, kt_) do {                                          \
    const u16* _g = ((op_) ? gb : ga) + (size_t)(kt_) * 64 + (size_t)(h_) * 128 * Kk; \
    u16* _d = &lds[bfi_][op_][(h_) * 128 * 64 + wave * 16 * 64];                \
    GLD_LDS16(_g,          _d);                                                 \
    GLD_LDS16(_g + 8 * Kk, _d + 512);                                           \
  } while (0)

#define LDA4(la_, mh_) do {                                                     \
    _Pragma("unroll") for (int _i = 0; _i < 4; ++_i) {                          \
      const int _o = aoff + ((mh_) * 4 + _i) * 1024;                            \
      af[_i][0] = *reinterpret_cast<const bf16x8*>((la_) + _o);                 \
      af[_i][1] = *reinterpret_cast<const bf16x8*>((la_) + (_o ^ 32));          \
    } } while (0)

#define LDBE(lb_) do {                                                          \
    _Pragma("unroll") for (int _n = 0; _n < 2; ++_n) {                          \
      const int _o = boff + _n * 1024;                                          \
      bfe[_n][0] = *reinterpret_cast<const bf16x8*>((lb_) + _o);                \
      bfe[_n][1] = *reinterpret_cast<const bf16x8*>((lb_) + (_o ^ 32));         \
    } } while (0)

#define LDBO(lb_) do {                                                          \
    _Pragma("unroll") for (int _n = 0; _n < 2; ++_n) {                          \
      const int _o = boff + (2 + _n) * 1024;                                    \
      bfo[_n][0] = *reinterpret_cast<const bf16x8*>((lb_) + _o);                \
      bfo[_n][1] = *reinterpret_cast<const bf16x8*>((lb_) + (_o ^ 32));         \
    } } while (0)

  // i-outer so af[i] retires after its 4 MFMAs -> scheduler can interleave next reads
#define MFMA_Q(mh_, BF_, nb_)                                                   \
  _Pragma("unroll") for (int i = 0; i < 4; ++i)                                 \
  _Pragma("unroll") for (int ks = 0; ks < 2; ++ks)                              \
  _Pragma("unroll") for (int n = 0; n < 2; ++n)                                 \
    acc[(mh_) * 4 + i][(nb_) + n] = __builtin_amdgcn_mfma_f32_16x16x32_bf16(    \
        af[i][ks], BF_[n][ks], acc[(mh_) * 4 + i][(nb_) + n], 0, 0, 0)

  const int KT = Kk >> 6;

  // ---- prologue: B(t0),A(t0)->buf0, B(t1),A(t1)->buf1; drain t0; pre-read t0 frags ----
  STAGE(0, 1, 0, 0); STAGE(0, 1, 1, 0);   // B(t0)
  STAGE(0, 0, 0, 0); STAGE(0, 0, 1, 0);   // A(t0)
  STAGE(1, 1, 0, 1); STAGE(1, 1, 1, 1);   // B(t1)
  STAGE(1, 0, 0, 1); STAGE(1, 0, 1, 1);   // A(t1)
  asm volatile("s_waitcnt vmcnt(8)" ::: "memory");
  SCHED0(); BAR(); SCHED0();
  LDA4((const u16*)&lds[0][0][0], 0);   // af = A(t0) mh0
  LDBE((const u16*)&lds[0][1][0]);      // bfe = B(t0) ni01

#define TILE(t_, CUR_) do {                                                     \
    const u16* la  = &lds[CUR_][0][0];                                          \
    const u16* lb  = &lds[CUR_][1][0];                                          \
    const u16* lan = &lds[CUR_ ^ 1][0][0];                                      \
    const u16* lbn = &lds[CUR_ ^ 1][1][0];                                      \
    const int kt2 = ((t_) + 2 < KT) ? (t_) + 2 : KT - 1;                        \
    /* p0: MFMA mh0*bfe ; read bfo(t) */                                        \
    SCHED0(); BAR(); SCHED0();                                                  \
    PRIO(1); MFMA_Q(0, bfe, 0); PRIO(0);                                        \
    LDBO(lb);                                                                   \
    /* p1: MFMA mh0*bfo ; read af=mh1(t) */                                     \
    SCHED0(); BAR(); SCHED0();                                                  \
    PRIO(1); MFMA_Q(0, bfo, 2); PRIO(0);                                        \
    LDA4(la, 1);                                                                \
    /* p2: stage B(t+2)->cur ; MFMA mh1*bfe */                                  \
    SCHED0(); BAR(); SCHED0();                                                  \
    STAGE(CUR_, 1, 0, kt2); STAGE(CUR_, 1, 1, kt2);                             \
    PRIO(1); MFMA_Q(1, bfe, 0); PRIO(0);                                        \
    /* p3: gate ; stage A(t+2)->cur ; MFMA mh1*bfo ; pre-read t+1 (mh0, ni01) */ \
    SCHED0();                                                                   \
    asm volatile("s_waitcnt vmcnt(4)" ::: "memory");                            \
    BAR(); SCHED0();                                                            \
    STAGE(CUR_, 0, 0, kt2); STAGE(CUR_, 0, 1, kt2);                             \
    PRIO(1); MFMA_Q(1, bfo, 2); PRIO(0);                                        \
    LDA4(lan, 0);                                                               \
    LDBE(lbn);                                                                  \
  } while (0)

  for (int kt = 0; kt < KT; kt += 2) {
    TILE(kt, 0);
    TILE(kt + 1, 1);
  }

  // ---- epilogue: out = acc*scale + bias ----
  const float sc = scale_p[0];
  float bv[4];
#pragma unroll
  for (int ni = 0; ni < 4; ++ni) bv[ni] = bias[n0 + wc * 64 + ni * 16 + r16];
#pragma unroll
  for (int mi = 0; mi < 8; ++mi) {
#pragma unroll
    for (int r = 0; r < 4; ++r) {
      // C/D layout (16x16x32): col = lane&15, row = (lane>>4)*4 + reg
      const int row = m0 + wr * 128 + mi * 16 + kq * 4 + r;
      float* cp = C + (size_t)row * Nn + (n0 + wc * 64 + r16);
#pragma unroll
      for (int ni = 0; ni < 4; ++ni)
        cp[ni * 16] = acc[mi][ni][r] * sc + bv[ni];
    }
  }
#undef STAGE
#undef LDA4
#undef LDBE
#undef LDBO
#undef MFMA_Q
#undef TILE
}

extern "C" void kernel_launch(void* const* d_in, const int* in_sizes, int n_in,
                              void* d_out, int out_size, void* d_ws, size_t ws_size,
                              hipStream_t stream) {
  (void)n_in; (void)out_size; (void)ws_size;
  const float* x  = (const float*)d_in[0];   // [M][K] fp32
  const float* w  = (const float*)d_in[1];   // [N][K] fp32 (fp8-representable values)
  const float* sc = (const float*)d_in[2];   // [1]
  const float* bs = (const float*)d_in[3];   // [N]
  float* out = (float*)d_out;                // [M][N] fp32

  const int N = in_sizes[3];        // 16384
  const int K = in_sizes[1] / N;    // 4096
  const int M = in_sizes[0] / K;    // 8192

  u16* xb = (u16*)d_ws;                      // [M][K] bf16  (64 MB)
  u16* wb = xb + (size_t)M * K;              // [N][K] bf16  (128 MB)

  cvt_f32_bf16<<<2048, 256, 0, stream>>>(x, xb, (M * K) / 8);
  cvt_f32_bf16<<<2048, 256, 0, stream>>>(w, wb, (N * K) / 8);

  const int NT = N / 256;
  const int nwg = (M / 256) * NT;            // 2048, % 8 == 0
  gemm256_8ph<<<nwg, 512, 0, stream>>>(xb, wb, sc, bs, out, N, K, NT);
}